// Round 1
// baseline (138.116 us; speedup 1.0000x reference)
//
#include <hip/hip_runtime.h>

typedef __bf16 bf16x8 __attribute__((ext_vector_type(8)));
typedef __bf16 bf16x4 __attribute__((ext_vector_type(4)));
typedef float  f32x4  __attribute__((ext_vector_type(4)));

// ---------------------------------------------------------------------------
// Prep: transpose f32 [R][C] -> bf16 [C][R]  (for MFMA B^T operands)
// ---------------------------------------------------------------------------
__global__ __launch_bounds__(256) void transpose_to_bf16(
    const float* __restrict__ src, __bf16* __restrict__ dst, int R, int C)
{
    __shared__ float tile[32][33];
    const int tx = threadIdx.x & 31, ty = threadIdx.x >> 5;
    const int r0 = blockIdx.y * 32, c0 = blockIdx.x * 32;
    #pragma unroll
    for (int i = ty; i < 32; i += 8)
        tile[i][tx] = src[(size_t)(r0 + i) * C + c0 + tx];
    __syncthreads();
    #pragma unroll
    for (int i = ty; i < 32; i += 8)
        dst[(size_t)(c0 + i) * R + r0 + tx] = (__bf16)tile[tx][i];
}

// ---------------------------------------------------------------------------
// bf16 MFMA GEMM:  Out[M][N] = op(A[M][K] @ B + bias[N])
// BT is B transposed: [N][K] bf16 row-major.
// A is f32 (converted on stage) or bf16.  RELU + bf16-out for the Q proj,
// plain f32-out for the output proj.
// 4 waves/block, 128xBN tile, BK=32, padded LDS (LD=40 -> 80B rows, 16B-aligned).
// ---------------------------------------------------------------------------
template<int BN, int WM, int WN, bool AF32, bool RELU, bool OBF16>
__global__ __launch_bounds__(256) void gemm_bias(
    const void* __restrict__ Ap, const __bf16* __restrict__ BT,
    const float* __restrict__ bias, void* __restrict__ Outp,
    int M, int N, int K)
{
    constexpr int BM = 128, BK = 32, LD = 40;
    constexpr int FM = BM / WM / 16, FN = BN / WN / 16;
    __shared__ __bf16 As[BM][LD];
    __shared__ __bf16 Bs[BN][LD];

    const int tid  = threadIdx.x;
    const int lane = tid & 63, wid = tid >> 6;
    const int wm = wid / WN, wn = wid % WN;
    const int m0 = blockIdx.y * BM, n0 = blockIdx.x * BN;
    const int r = lane & 15, g = lane >> 4;

    f32x4 acc[FM][FN];
    const f32x4 zero = {0.f, 0.f, 0.f, 0.f};
    #pragma unroll
    for (int mi = 0; mi < FM; ++mi)
        #pragma unroll
        for (int ni = 0; ni < FN; ++ni)
            acc[mi][ni] = zero;

    for (int k0 = 0; k0 < K; k0 += BK) {
        __syncthreads();
        // ---- stage A tile (128 x 32) ----
        if constexpr (AF32) {
            const float* A = (const float*)Ap;
            #pragma unroll
            for (int i = 0; i < (BM * BK / 4) / 256; ++i) {     // 4 iters
                int idx = tid + i * 256;
                int row = idx >> 3, c4 = (idx & 7) * 4;
                f32x4 v = *(const f32x4*)(A + (size_t)(m0 + row) * K + k0 + c4);
                bf16x4 b;
                b[0] = (__bf16)v[0]; b[1] = (__bf16)v[1];
                b[2] = (__bf16)v[2]; b[3] = (__bf16)v[3];
                *(bf16x4*)&As[row][c4] = b;
            }
        } else {
            const __bf16* A = (const __bf16*)Ap;
            #pragma unroll
            for (int i = 0; i < (BM * BK / 8) / 256; ++i) {     // 2 iters
                int idx = tid + i * 256;
                int row = idx >> 2, s8 = (idx & 3) * 8;
                *(bf16x8*)&As[row][s8] =
                    *(const bf16x8*)(A + (size_t)(m0 + row) * K + k0 + s8);
            }
        }
        // ---- stage B tile (BN x 32) from BT[N][K] ----
        #pragma unroll
        for (int i = 0; i < (BN * 4) / 256; ++i) {
            int idx = tid + i * 256;
            int row = idx >> 2, s8 = (idx & 3) * 8;
            *(bf16x8*)&Bs[row][s8] =
                *(const bf16x8*)(BT + (size_t)(n0 + row) * K + k0 + s8);
        }
        __syncthreads();

        // ---- MFMA: each wave owns a (FM*16) x (FN*16) sub-tile ----
        bf16x8 af[FM], bfr[FN];
        #pragma unroll
        for (int mi = 0; mi < FM; ++mi)
            af[mi] = *(const bf16x8*)&As[wm * (FM * 16) + mi * 16 + r][g * 8];
        #pragma unroll
        for (int ni = 0; ni < FN; ++ni)
            bfr[ni] = *(const bf16x8*)&Bs[wn * (FN * 16) + ni * 16 + r][g * 8];
        #pragma unroll
        for (int mi = 0; mi < FM; ++mi)
            #pragma unroll
            for (int ni = 0; ni < FN; ++ni)
                acc[mi][ni] = __builtin_amdgcn_mfma_f32_16x16x32_bf16(
                    af[mi], bfr[ni], acc[mi][ni], 0, 0, 0);
    }

    // ---- epilogue: D col = lane&15, row = 4*(lane>>4)+q ----
    const int orow = m0 + wm * (FM * 16) + g * 4;
    const int ocol = n0 + wn * (FN * 16) + r;
    #pragma unroll
    for (int ni = 0; ni < FN; ++ni) {
        const float bb = bias[ocol + ni * 16];
        #pragma unroll
        for (int mi = 0; mi < FM; ++mi) {
            #pragma unroll
            for (int q = 0; q < 4; ++q) {
                float v = acc[mi][ni][q] + bb;
                if constexpr (RELU) v = fmaxf(v, 0.f);
                const size_t o = (size_t)(orow + mi * 16 + q) * N + ocol + ni * 16;
                if constexpr (OBF16) ((__bf16*)Outp)[o] = (__bf16)v;
                else                 ((float*)Outp)[o]  = v;
            }
        }
    }
}

// ---------------------------------------------------------------------------
// Fused memory attention.  1 wave = 1 token, 4 waves/block, wave-private LDS
// slabs (no barriers needed).  Streams memories in 16-row chunks:
//   k = relu(mem + addr);  s[h][m] = sum_d q[h][d]*k[m][d]
//   num[h][e] += sum_m s[h][m]*mem[m][e];  den[h] += sum_m s[h][m]
//   attn = num / (den + eps)   -> bf16 [n][512]
// Lane map: h = lane>>3 (8 heads), eg/mg = lane&7.
// Padded LDS (stride 68 f32 / 20 f32) -> conflict-free or 2-way (free).
// ---------------------------------------------------------------------------
__global__ __launch_bounds__(256) void memory_attn(
    const __bf16* __restrict__ Q,      // [N][512] bf16 (relu'd q proj)
    const float*  __restrict__ mem,    // [N][128][64] f32
    const float*  __restrict__ adr,    // [128][64] f32
    __bf16* __restrict__ attn)         // [N][512] bf16
{
    constexpr int MC = 16, NCH = 128 / MC;
    __shared__ float kt[4][MC][68];
    __shared__ float mt[4][MC][68];
    __shared__ float sl[4][8][20];
    __shared__ float ql[4][8][68];

    const int tid = threadIdx.x, lane = tid & 63, w = tid >> 6;
    const int n = blockIdx.x * 4 + w;
    const int h = lane >> 3, eg = lane & 7;

    // stage q (f32) once per token: lane covers flat elements [lane*8, +8)
    {
        bf16x8 qv = *(const bf16x8*)(Q + (size_t)n * 512 + lane * 8);
        f32x4 a, b;
        #pragma unroll
        for (int j = 0; j < 4; ++j) { a[j] = (float)qv[j]; b[j] = (float)qv[4 + j]; }
        const int qh = lane >> 3, qd = (lane & 7) * 8;
        *(f32x4*)&ql[w][qh][qd]     = a;
        *(f32x4*)&ql[w][qh][qd + 4] = b;
    }

    float num[8] = {0.f, 0.f, 0.f, 0.f, 0.f, 0.f, 0.f, 0.f};
    float den = 0.f;

    for (int c = 0; c < NCH; ++c) {
        const int mb = c * MC;
        // ---- stage chunk: mem raw (f32) + k = relu(mem+addr) ----
        #pragma unroll
        for (int i = 0; i < 4; ++i) {
            const int f4 = i * 64 + lane;
            const int m = f4 >> 4, e = (f4 & 15) * 4;
            f32x4 mv = *(const f32x4*)(mem + ((size_t)n * 128 + mb + m) * 64 + e);
            f32x4 av = *(const f32x4*)(adr + (size_t)(mb + m) * 64 + e);
            f32x4 kv;
            #pragma unroll
            for (int j = 0; j < 4; ++j) kv[j] = fmaxf(mv[j] + av[j], 0.f);
            *(f32x4*)&mt[w][m][e] = mv;
            *(f32x4*)&kt[w][m][e] = kv;
        }
        // ---- s phase: lane (h, mg=eg) computes s[h][eg] and s[h][eg+8] ----
        float s0 = 0.f, s1 = 0.f;
        #pragma unroll
        for (int jb = 0; jb < 8; ++jb) {
            f32x4 q0 = *(const f32x4*)&ql[w][h][jb * 8];
            f32x4 q1 = *(const f32x4*)&ql[w][h][jb * 8 + 4];
            f32x4 k00 = *(const f32x4*)&kt[w][eg][jb * 8];
            f32x4 k01 = *(const f32x4*)&kt[w][eg][jb * 8 + 4];
            f32x4 k10 = *(const f32x4*)&kt[w][eg + 8][jb * 8];
            f32x4 k11 = *(const f32x4*)&kt[w][eg + 8][jb * 8 + 4];
            #pragma unroll
            for (int j = 0; j < 4; ++j) {
                s0 = fmaf(q0[j], k00[j], s0); s0 = fmaf(q1[j], k01[j], s0);
                s1 = fmaf(q0[j], k10[j], s1); s1 = fmaf(q1[j], k11[j], s1);
            }
        }
        sl[w][h][eg]     = s0;
        sl[w][h][eg + 8] = s1;
        // ---- num phase: lane (h, eg) owns e = eg*8 .. +8 ----
        #pragma unroll
        for (int m = 0; m < MC; ++m) {
            const float sv = sl[w][h][m];
            den += sv;
            f32x4 v0 = *(const f32x4*)&mt[w][m][eg * 8];
            f32x4 v1 = *(const f32x4*)&mt[w][m][eg * 8 + 4];
            #pragma unroll
            for (int j = 0; j < 4; ++j) {
                num[j]     = fmaf(sv, v0[j], num[j]);
                num[4 + j] = fmaf(sv, v1[j], num[4 + j]);
            }
        }
    }

    const float inv = 1.f / (den + 1e-5f);
    bf16x8 o;
    #pragma unroll
    for (int j = 0; j < 8; ++j) o[j] = (__bf16)(num[j] * inv);
    *(bf16x8*)(attn + (size_t)n * 512 + h * 64 + eg * 8) = o;
}

// ---------------------------------------------------------------------------
extern "C" void kernel_launch(void* const* d_in, const int* in_sizes, int n_in,
                              void* d_out, int out_size, void* d_ws, size_t ws_size,
                              hipStream_t stream)
{
    const float* query     = (const float*)d_in[0];
    const float* addresses = (const float*)d_in[1];
    const float* memories  = (const float*)d_in[2];
    const float* Wq        = (const float*)d_in[3];
    const float* bq        = (const float*)d_in[4];
    const float* Wo        = (const float*)d_in[5];
    const float* bo        = (const float*)d_in[6];
    float* out = (float*)d_out;

    char* ws = (char*)d_ws;
    __bf16* WqT = (__bf16*)(ws);                       // [512][1024]  1 MB
    __bf16* WoT = (__bf16*)(ws + (1 << 20));           // [1024][512]  1 MB
    __bf16* Qb  = (__bf16*)(ws + (2 << 20));           // [8192][512]  8 MB
    __bf16* Ab  = (__bf16*)(ws + (10 << 20));          // [8192][512]  8 MB

    // Wq: [1024][512] -> WqT [512][1024] bf16 ; Wo: [512][1024] -> WoT [1024][512]
    transpose_to_bf16<<<dim3(512 / 32, 1024 / 32), 256, 0, stream>>>(Wq, WqT, 1024, 512);
    transpose_to_bf16<<<dim3(1024 / 32, 512 / 32), 256, 0, stream>>>(Wo, WoT, 512, 1024);

    // Q = relu(query @ Wq + bq)  -> bf16 [8192][512]
    gemm_bias<64, 4, 1, true, true, true>
        <<<dim3(512 / 64, 8192 / 128), 256, 0, stream>>>(
            query, WqT, bq, Qb, 8192, 512, 1024);

    // fused per-token linear memory read -> attn bf16 [8192][512]
    memory_attn<<<dim3(8192 / 4), 256, 0, stream>>>(Qb, memories, addresses, Ab);

    // out = attn @ Wo + bo  -> f32 [8192][1024]
    gemm_bias<128, 2, 2, false, false, false>
        <<<dim3(1024 / 128, 8192 / 128), 256, 0, stream>>>(
            Ab, WoT, bo, out, 8192, 1024, 512);
}

// Round 2
// 128.585 us; speedup vs baseline: 1.0741x; 1.0741x over previous
//
#include <hip/hip_runtime.h>

typedef __bf16 bf16x8 __attribute__((ext_vector_type(8)));
typedef __bf16 bf16x4 __attribute__((ext_vector_type(4)));
typedef __bf16 bf16x2 __attribute__((ext_vector_type(2)));
typedef float  f32x4  __attribute__((ext_vector_type(4)));

// ---------------------------------------------------------------------------
// Prep: transpose f32 [R][C] -> bf16 [C][R]  (for MFMA B^T operands)
// ---------------------------------------------------------------------------
__global__ __launch_bounds__(256) void transpose_to_bf16(
    const float* __restrict__ src, __bf16* __restrict__ dst, int R, int C)
{
    __shared__ float tile[32][33];
    const int tx = threadIdx.x & 31, ty = threadIdx.x >> 5;
    const int r0 = blockIdx.y * 32, c0 = blockIdx.x * 32;
    #pragma unroll
    for (int i = ty; i < 32; i += 8)
        tile[i][tx] = src[(size_t)(r0 + i) * C + c0 + tx];
    __syncthreads();
    #pragma unroll
    for (int i = ty; i < 32; i += 8)
        dst[(size_t)(c0 + i) * R + r0 + tx] = (__bf16)tile[tx][i];
}

// ---------------------------------------------------------------------------
// bf16 MFMA GEMM:  Out[M][N] = op(A[M][K] @ B + bias[N])   (unchanged, proven)
// ---------------------------------------------------------------------------
template<int BN, int WM, int WN, bool AF32, bool RELU, bool OBF16>
__global__ __launch_bounds__(256) void gemm_bias(
    const void* __restrict__ Ap, const __bf16* __restrict__ BT,
    const float* __restrict__ bias, void* __restrict__ Outp,
    int M, int N, int K)
{
    constexpr int BM = 128, BK = 32, LD = 40;
    constexpr int FM = BM / WM / 16, FN = BN / WN / 16;
    __shared__ __bf16 As[BM][LD];
    __shared__ __bf16 Bs[BN][LD];

    const int tid  = threadIdx.x;
    const int lane = tid & 63, wid = tid >> 6;
    const int wm = wid / WN, wn = wid % WN;
    const int m0 = blockIdx.y * BM, n0 = blockIdx.x * BN;
    const int r = lane & 15, g = lane >> 4;

    f32x4 acc[FM][FN];
    const f32x4 zero = {0.f, 0.f, 0.f, 0.f};
    #pragma unroll
    for (int mi = 0; mi < FM; ++mi)
        #pragma unroll
        for (int ni = 0; ni < FN; ++ni)
            acc[mi][ni] = zero;

    for (int k0 = 0; k0 < K; k0 += BK) {
        __syncthreads();
        if constexpr (AF32) {
            const float* A = (const float*)Ap;
            #pragma unroll
            for (int i = 0; i < (BM * BK / 4) / 256; ++i) {
                int idx = tid + i * 256;
                int row = idx >> 3, c4 = (idx & 7) * 4;
                f32x4 v = *(const f32x4*)(A + (size_t)(m0 + row) * K + k0 + c4);
                bf16x4 b;
                b[0] = (__bf16)v[0]; b[1] = (__bf16)v[1];
                b[2] = (__bf16)v[2]; b[3] = (__bf16)v[3];
                *(bf16x4*)&As[row][c4] = b;
            }
        } else {
            const __bf16* A = (const __bf16*)Ap;
            #pragma unroll
            for (int i = 0; i < (BM * BK / 8) / 256; ++i) {
                int idx = tid + i * 256;
                int row = idx >> 2, s8 = (idx & 3) * 8;
                *(bf16x8*)&As[row][s8] =
                    *(const bf16x8*)(A + (size_t)(m0 + row) * K + k0 + s8);
            }
        }
        #pragma unroll
        for (int i = 0; i < (BN * 4) / 256; ++i) {
            int idx = tid + i * 256;
            int row = idx >> 2, s8 = (idx & 3) * 8;
            *(bf16x8*)&Bs[row][s8] =
                *(const bf16x8*)(BT + (size_t)(n0 + row) * K + k0 + s8);
        }
        __syncthreads();

        bf16x8 af[FM], bfr[FN];
        #pragma unroll
        for (int mi = 0; mi < FM; ++mi)
            af[mi] = *(const bf16x8*)&As[wm * (FM * 16) + mi * 16 + r][g * 8];
        #pragma unroll
        for (int ni = 0; ni < FN; ++ni)
            bfr[ni] = *(const bf16x8*)&Bs[wn * (FN * 16) + ni * 16 + r][g * 8];
        #pragma unroll
        for (int mi = 0; mi < FM; ++mi)
            #pragma unroll
            for (int ni = 0; ni < FN; ++ni)
                acc[mi][ni] = __builtin_amdgcn_mfma_f32_16x16x32_bf16(
                    af[mi], bfr[ni], acc[mi][ni], 0, 0, 0);
    }

    const int orow = m0 + wm * (FM * 16) + g * 4;
    const int ocol = n0 + wn * (FN * 16) + r;
    #pragma unroll
    for (int ni = 0; ni < FN; ++ni) {
        const float bb = bias[ocol + ni * 16];
        #pragma unroll
        for (int mi = 0; mi < FM; ++mi) {
            #pragma unroll
            for (int q = 0; q < 4; ++q) {
                float v = acc[mi][ni][q] + bb;
                if constexpr (RELU) v = fmaxf(v, 0.f);
                const size_t o = (size_t)(orow + mi * 16 + q) * N + ocol + ni * 16;
                if constexpr (OBF16) ((__bf16*)Outp)[o] = (__bf16)v;
                else                 ((float*)Outp)[o]  = v;
            }
        }
    }
}

// ---------------------------------------------------------------------------
// Fused memory attention, MFMA version.  1 wave = 1 token, wave-private LDS,
// no barriers.  Per 32-m chunk:
//   stage:   k = relu(mem+addr) -> LDS (swizzled rows);  memT (bf16, packed
//            row-pairs, permuted columns kappa) -> LDS (80B padded rows)
//   stage A: S^T[m][h] = mfma(k_rows, q_rows)   (2 M-blocks x 2 K-steps)
//   link:    A-frag for stage B is LANE-LOCAL: pa[j] = bf16(sA[j>>2][j&3])
//            (guaranteed by the kappa column permutation of memT)
//   stage B: num[h][e] += mfma(pa, memT-frag)   (4 N-blocks)
//   den falls out as sum of S^T rows + 2 shfl_xor.
// ---------------------------------------------------------------------------
__device__ __forceinline__ int kbyte(int m, int e) {
    return m * 128 + ((((e >> 3) ^ (m & 7))) << 4) + (e & 7) * 2;
}

__global__ __launch_bounds__(256) void memory_attn_mfma(
    const __bf16* __restrict__ Q,      // [N][512] bf16 (relu'd q proj)
    const float*  __restrict__ mem,    // [N][128][64] f32
    const float*  __restrict__ adr,    // [128][64] f32
    __bf16* __restrict__ attn)         // [N][512] bf16
{
    __shared__ __align__(16) unsigned char kbuf[4][4096];   // k: 32 x 128B (swizzled)
    __shared__ __align__(16) unsigned char tbuf[4][5120];   // memT: 64 x 80B
    __shared__ float denl[4][8];

    const int tid = threadIdx.x, lane = tid & 63, w = tid >> 6;
    const int n = blockIdx.x * 4 + w;
    const int v = lane & 15, g = lane >> 4;

    unsigned char* kb = kbuf[w];
    unsigned char* tb = tbuf[w];

    // q fragments (stage-A B-operand): lane holds q[h=v][d = 32*kst + 8g .. +8]
    // (v>=8 reads into the next token's q: finite garbage, never consumed)
    const __bf16* qp = Q + (size_t)n * 512 + v * 64 + 8 * g;
    const bf16x8 qf0 = *(const bf16x8*)(qp);
    const bf16x8 qf1 = *(const bf16x8*)(qp + 32);

    f32x4 acc[4];
    const f32x4 zero = {0.f, 0.f, 0.f, 0.f};
    #pragma unroll
    for (int nb = 0; nb < 4; ++nb) acc[nb] = zero;
    float psum = 0.f;

    for (int c = 0; c < 4; ++c) {
        const int mb = c * 32;
        // ---- stage chunk: 4 paired-row iterations ----
        #pragma unroll
        for (int i = 0; i < 4; ++i) {
            const int mo = 8 * i + 2 * g;           // even row of the pair
            const int e  = 4 * v;
            const float* pm = mem + (((size_t)n * 128 + mb + mo) * 64 + e);
            const f32x4 m0 = *(const f32x4*)pm;
            const f32x4 m1 = *(const f32x4*)(pm + 64);
            const float* pav = adr + ((size_t)(mb + mo) * 64 + e);
            const f32x4 a0 = *(const f32x4*)pav;
            const f32x4 a1 = *(const f32x4*)(pav + 64);
            bf16x4 k0, k1;
            #pragma unroll
            for (int j = 0; j < 4; ++j) {
                k0[j] = (__bf16)fmaxf(m0[j] + a0[j], 0.f);
                k1[j] = (__bf16)fmaxf(m1[j] + a1[j], 0.f);
            }
            *(bf16x4*)(kb + kbyte(mo,     e)) = k0;
            *(bf16x4*)(kb + kbyte(mo + 1, e)) = k1;
            // memT: column permutation kappa; pair (mo, mo+1) -> (kap, kap+1)
            const int kap = 8 * ((mo >> 2) & 3) + 4 * (mo >> 4) + (mo & 3);
            #pragma unroll
            for (int j2 = 0; j2 < 4; ++j2) {
                bf16x2 p = { (__bf16)m0[j2], (__bf16)m1[j2] };
                *(bf16x2*)(tb + (size_t)(e + j2) * 80 + kap * 2) = p;
            }
        }

        // ---- stage A: S^T = k . q^T  (rows m, cols h) ----
        f32x4 sA0 = zero, sA1 = zero;
        {
            const bf16x8 a00 = *(const bf16x8*)(kb + kbyte(v,      8 * g));
            const bf16x8 a01 = *(const bf16x8*)(kb + kbyte(v,      32 + 8 * g));
            const bf16x8 a10 = *(const bf16x8*)(kb + kbyte(v + 16, 8 * g));
            const bf16x8 a11 = *(const bf16x8*)(kb + kbyte(v + 16, 32 + 8 * g));
            sA0 = __builtin_amdgcn_mfma_f32_16x16x32_bf16(a00, qf0, sA0, 0, 0, 0);
            sA0 = __builtin_amdgcn_mfma_f32_16x16x32_bf16(a01, qf1, sA0, 0, 0, 0);
            sA1 = __builtin_amdgcn_mfma_f32_16x16x32_bf16(a10, qf0, sA1, 0, 0, 0);
            sA1 = __builtin_amdgcn_mfma_f32_16x16x32_bf16(a11, qf1, sA1, 0, 0, 0);
        }
        psum += sA0[0] + sA0[1] + sA0[2] + sA0[3]
              + sA1[0] + sA1[1] + sA1[2] + sA1[3];

        // ---- lane-local A-frag for stage B ----
        bf16x8 pa;
        #pragma unroll
        for (int q = 0; q < 4; ++q) {
            pa[q]     = (__bf16)sA0[q];
            pa[4 + q] = (__bf16)sA1[q];
        }

        // ---- stage B: num += S . mem  (rows h, cols e) ----
        #pragma unroll
        for (int nb = 0; nb < 4; ++nb) {
            const bf16x8 bf = *(const bf16x8*)(tb + (size_t)(16 * nb + v) * 80 + 16 * g);
            acc[nb] = __builtin_amdgcn_mfma_f32_16x16x32_bf16(pa, bf, acc[nb], 0, 0, 0);
        }
    }

    // ---- epilogue: den reduce + divide + store ----
    psum += __shfl_xor(psum, 16);
    psum += __shfl_xor(psum, 32);
    if (lane < 8) denl[w][lane] = psum;

    if (g < 2) {
        const f32x4 d4 = *(const f32x4*)&denl[w][4 * g];
        float inv[4];
        #pragma unroll
        for (int q = 0; q < 4; ++q) inv[q] = 1.f / (d4[q] + 1e-5f);
        #pragma unroll
        for (int nb = 0; nb < 4; ++nb) {
            #pragma unroll
            for (int q = 0; q < 4; ++q) {
                attn[(size_t)n * 512 + (4 * g + q) * 64 + 16 * nb + v] =
                    (__bf16)(acc[nb][q] * inv[q]);
            }
        }
    }
}

// ---------------------------------------------------------------------------
extern "C" void kernel_launch(void* const* d_in, const int* in_sizes, int n_in,
                              void* d_out, int out_size, void* d_ws, size_t ws_size,
                              hipStream_t stream)
{
    const float* query     = (const float*)d_in[0];
    const float* addresses = (const float*)d_in[1];
    const float* memories  = (const float*)d_in[2];
    const float* Wq        = (const float*)d_in[3];
    const float* bq        = (const float*)d_in[4];
    const float* Wo        = (const float*)d_in[5];
    const float* bo        = (const float*)d_in[6];
    float* out = (float*)d_out;

    char* ws = (char*)d_ws;
    __bf16* WqT = (__bf16*)(ws);                       // [512][1024]  1 MB
    __bf16* WoT = (__bf16*)(ws + (1 << 20));           // [1024][512]  1 MB
    __bf16* Qb  = (__bf16*)(ws + (2 << 20));           // [8192][512]  8 MB
    __bf16* Ab  = (__bf16*)(ws + (10 << 20));          // [8192][512]  8 MB

    transpose_to_bf16<<<dim3(512 / 32, 1024 / 32), 256, 0, stream>>>(Wq, WqT, 1024, 512);
    transpose_to_bf16<<<dim3(1024 / 32, 512 / 32), 256, 0, stream>>>(Wo, WoT, 512, 1024);

    // Q = relu(query @ Wq + bq)  -> bf16 [8192][512]
    gemm_bias<64, 4, 1, true, true, true>
        <<<dim3(512 / 64, 8192 / 128), 256, 0, stream>>>(
            query, WqT, bq, Qb, 8192, 512, 1024);

    // fused per-token linear memory read (MFMA) -> attn bf16 [8192][512]
    memory_attn_mfma<<<dim3(8192 / 4), 256, 0, stream>>>(Qb, memories, addresses, Ab);

    // out = attn @ Wo + bo  -> f32 [8192][1024]
    gemm_bias<128, 2, 2, false, false, false>
        <<<dim3(1024 / 128, 8192 / 128), 256, 0, stream>>>(
            Ab, WoT, bo, out, 8192, 1024, 512);
}